// Round 2
// baseline (757.690 us; speedup 1.0000x reference)
//
#include <hip/hip_runtime.h>
#include <stdint.h>

#define T_TOK 4096
#define DM 1024
#define DF 4096
#define NE 8

typedef __attribute__((ext_vector_type(8))) short bf16x8;
typedef __attribute__((ext_vector_type(4))) float f32x4;

__device__ __forceinline__ float b2f(unsigned short u) {
    union { unsigned int i; float f; } v; v.i = ((unsigned int)u) << 16; return v.f;
}
__device__ __forceinline__ unsigned short f2b(float f) {
    unsigned int i = __float_as_uint(f);
    unsigned int r = (i + 0x7FFFu + ((i >> 16) & 1u)) >> 16;
    return (unsigned short)r;
}
__device__ __forceinline__ void load_lds16(const void* g, void* l) {
    __builtin_amdgcn_global_load_lds((__attribute__((address_space(1))) void*)(g),
                                     (__attribute__((address_space(3))) void*)(l), 16, 0, 0);
}

__device__ __forceinline__ float fexp2(float x) {
#if __has_builtin(__builtin_amdgcn_exp2f)
    return __builtin_amdgcn_exp2f(x);
#else
    return exp2f(x);
#endif
}
__device__ __forceinline__ float frcp(float x) {
#if __has_builtin(__builtin_amdgcn_rcpf)
    return __builtin_amdgcn_rcpf(x);
#else
    return 1.0f / x;
#endif
}

// exact-erf GELU via A&S 7.1.26 (|erf err| <= 1.5e-7, far below bf16 noise)
__device__ __forceinline__ float gelu_f(float h) {
    float z = h * 0.70710678118654752f;
    float az = fabsf(z);
    float t = frcp(1.0f + 0.3275911f * az);
    float p = ((((1.061405429f * t - 1.453152027f) * t + 1.421413741f) * t
                - 0.284496736f) * t + 0.254829592f) * t;
    float e = fexp2(-1.4426950408889634f * az * az);
    float er = 1.0f - p * e;
    er = (z < 0.f) ? -er : er;
    return 0.5f * h * (1.0f + er);
}
__device__ __forceinline__ float silu_f(float h) {
    return h * frcp(1.0f + fexp2(-1.4426950408889634f * h));
}

// chunked-8 XCD swizzle: hw id H (XCD = H&7) -> logical id L such that each XCD
// gets chunks of 8 consecutive logical blocks (A-panel group stays on one XCD).
// Bijective when nwg % 64 == 0 (8192 and 2048 both qualify).
__device__ __forceinline__ int swz_bid(int H) {
    int x = H & 7, k = H >> 3;
    return 8 * x + 64 * (k >> 3) + (k & 7);
}

// ---------------- dtype detector ----------------
__global__ __launch_bounds__(256) void detect_kernel(const unsigned short* __restrict__ xu,
                                                     int* __restrict__ flag) {
    const int i = (blockIdx.x * 256 + threadIdx.x) * 4;
    uint2 v = *(const uint2*)&xu[i];
    unsigned int a = v.x, b = v.y;
    int found = 0;
    if (((a >> 7)  & 0xFF) == 0xFF) found = 1;
    if (((a >> 23) & 0xFF) == 0xFF) found = 1;
    if (((b >> 7)  & 0xFF) == 0xFF) found = 1;
    if (((b >> 23) & 0xFF) == 0xFF) found = 1;
    if (__ballot(found) != 0 && (threadIdx.x & 63) == 0) atomicOr(flag, 1);
}

// ---------------- x -> bf16 (cast or copy) ----------------
__global__ __launch_bounds__(256) void convx_kernel(const void* __restrict__ xin,
                                                    const int* __restrict__ flag,
                                                    unsigned short* __restrict__ xb) {
    const size_t i = ((size_t)blockIdx.x * 256 + threadIdx.x) * 8;
    if (*flag) {
        const float* xf = (const float*)xin + i;
        float4 a = *(const float4*)xf;
        float4 b = *(const float4*)(xf + 4);
        alignas(16) unsigned short t[8] = { f2b(a.x), f2b(a.y), f2b(a.z), f2b(a.w),
                                            f2b(b.x), f2b(b.y), f2b(b.z), f2b(b.w) };
        *(uint4*)(xb + i) = *(const uint4*)t;
    } else {
        *(uint4*)(xb + i) = *(const uint4*)((const unsigned short*)xin + i);
    }
}

// ---------------- b1 + b2 -> fp32 (one launch) ----------------
__global__ void convf_kernel(const void* __restrict__ b1, const void* __restrict__ b2,
                             const int* __restrict__ flag,
                             float* __restrict__ d1, float* __restrict__ d2) {
    const int i = blockIdx.x * 256 + threadIdx.x;
    const int isf = *flag;
    if (i < NE * DF) {
        d1[i] = isf ? ((const float*)b1)[i] : b2f(((const unsigned short*)b1)[i]);
    } else {
        int j = i - NE * DF;
        d2[j] = isf ? ((const float*)b2)[j] : b2f(((const unsigned short*)b2)[j]);
    }
}

// ---------------- W1 and W2 transpose+cast in ONE launch ----------------
// z < 8: W1 expert z (R=DM, C=DF).  z >= 8: W2 expert z-8 (R=DF, C=DM).
__global__ __launch_bounds__(256) void transpose_kernel(
    const void* __restrict__ in1, const void* __restrict__ in2,
    unsigned short* __restrict__ out1, unsigned short* __restrict__ out2,
    const int* __restrict__ flag) {
    __shared__ unsigned short tile[64][65];
    const int isf = *flag;
    const void* in; unsigned short* out;
    int R, C, rt, ct; size_t base;
    if (blockIdx.z < 8) {
        in = in1; out = out1; R = DM; C = DF;
        base = (size_t)blockIdx.z * R * C;
        rt = blockIdx.y; ct = blockIdx.x;                 // 16 x 64 tiles
    } else {
        in = in2; out = out2; R = DF; C = DM;
        base = (size_t)(blockIdx.z - 8) * R * C;
        ct = blockIdx.x & 15;                              // 64 x 16 tiles
        rt = (blockIdx.y << 2) | (blockIdx.x >> 4);
    }
    const int r0 = rt * 64, c0 = ct * 64;
    const int lr = threadIdx.x >> 2;
    const int lc = (threadIdx.x & 3) * 16;
    if (isf) {
        const float* src = (const float*)in + base + (size_t)(r0 + lr) * C + c0 + lc;
#pragma unroll
        for (int q = 0; q < 4; q++) {
            float4 v = *(const float4*)(src + q * 4);
            tile[lr][lc + q * 4 + 0] = f2b(v.x);
            tile[lr][lc + q * 4 + 1] = f2b(v.y);
            tile[lr][lc + q * 4 + 2] = f2b(v.z);
            tile[lr][lc + q * 4 + 3] = f2b(v.w);
        }
    } else {
        const unsigned short* src = (const unsigned short*)in + base + (size_t)(r0 + lr) * C + c0 + lc;
#pragma unroll
        for (int q = 0; q < 2; q++) {
            uint4 v = *(const uint4*)(src + q * 8);
            unsigned int w[4] = { v.x, v.y, v.z, v.w };
#pragma unroll
            for (int j = 0; j < 4; j++) {
                tile[lr][lc + q * 8 + 2 * j]     = (unsigned short)(w[j] & 0xffff);
                tile[lr][lc + q * 8 + 2 * j + 1] = (unsigned short)(w[j] >> 16);
            }
        }
    }
    __syncthreads();
    const int oc = threadIdx.x >> 2;
    const int oj = (threadIdx.x & 3) * 16;
    alignas(16) unsigned short tmp[16];
#pragma unroll
    for (int j = 0; j < 16; j++) tmp[j] = tile[oj + j][oc];
    unsigned short* dst = out + base + (size_t)(c0 + oc) * R + r0 + oj;
    *(uint4*)(dst) = *(const uint4*)(tmp);
    *(uint4*)(dst + 8) = *(const uint4*)(tmp + 8);
}

// ---------------- gate ----------------
__global__ __launch_bounds__(256) void gate_kernel(
    const void* __restrict__ x, const void* __restrict__ Wg, const void* __restrict__ bg,
    const int* __restrict__ flag, int* __restrict__ cnt,
    int* __restrict__ tok_e, float* __restrict__ tok_s) {
    const int isf = *flag;
    const int wave = threadIdx.x >> 6, lane = threadIdx.x & 63;
    const int t = blockIdx.x * 4 + wave;
    float p[8] = {0.f,0.f,0.f,0.f,0.f,0.f,0.f,0.f};
    if (isf) {
        const float* xr = (const float*)x + (size_t)t * DM;
        const float* wg = (const float*)Wg;
        for (int i = lane; i < DM; i += 64) {
            float xv = xr[i];
            float4 a = *(const float4*)(wg + (size_t)i * 8);
            float4 b = *(const float4*)(wg + (size_t)i * 8 + 4);
            p[0] += xv * a.x; p[1] += xv * a.y; p[2] += xv * a.z; p[3] += xv * a.w;
            p[4] += xv * b.x; p[5] += xv * b.y; p[6] += xv * b.z; p[7] += xv * b.w;
        }
    } else {
        const unsigned short* xr = (const unsigned short*)x + (size_t)t * DM;
        const unsigned short* wg = (const unsigned short*)Wg;
        for (int i = lane; i < DM; i += 64) {
            float xv = b2f(xr[i]);
            uint4 wv = *(const uint4*)(wg + (size_t)i * 8);
            p[0] += xv * b2f((unsigned short)(wv.x & 0xffff));
            p[1] += xv * b2f((unsigned short)(wv.x >> 16));
            p[2] += xv * b2f((unsigned short)(wv.y & 0xffff));
            p[3] += xv * b2f((unsigned short)(wv.y >> 16));
            p[4] += xv * b2f((unsigned short)(wv.z & 0xffff));
            p[5] += xv * b2f((unsigned short)(wv.z >> 16));
            p[6] += xv * b2f((unsigned short)(wv.w & 0xffff));
            p[7] += xv * b2f((unsigned short)(wv.w >> 16));
        }
    }
    for (int off = 32; off > 0; off >>= 1)
        for (int e = 0; e < 8; e++) p[e] += __shfl_down(p[e], off);
    if (lane == 0) {
        for (int e = 0; e < 8; e++)
            p[e] += isf ? ((const float*)bg)[e] : b2f(((const unsigned short*)bg)[e]);
        int e0 = 0;
        for (int e = 1; e < 8; e++) if (p[e] > p[e0]) e0 = e;
        int e1 = (e0 == 0) ? 1 : 0;
        for (int e = 0; e < 8; e++) if (e != e0 && p[e] > p[e1]) e1 = e;
        float z = expf(p[e1] - p[e0]);
        float s0 = 1.f / (1.f + z);
        tok_e[2 * t] = e0; tok_e[2 * t + 1] = e1;
        tok_s[2 * t] = s0; tok_s[2 * t + 1] = z * s0;
        atomicAdd(&cnt[e0], 1); atomicAdd(&cnt[e1], 1);
    }
}

__global__ void scan_kernel(const int* __restrict__ cnt, int* __restrict__ offs) {
    if (threadIdx.x == 0) {
        int s = 0;
        for (int e = 0; e < NE; e++) { offs[e] = s; s += cnt[e]; }
    }
}

__global__ __launch_bounds__(256) void place_kernel(
    const int* __restrict__ tok_e, const int* __restrict__ offs, int* __restrict__ cnt2,
    int* __restrict__ tok_list, int* __restrict__ slot_of) {
    const int t = blockIdx.x * 256 + threadIdx.x;
    for (int k = 0; k < 2; k++) {
        int e = tok_e[2 * t + k];
        int slot = atomicAdd(&cnt2[e], 1);
        int idx = offs[e] + slot;
        tok_list[idx] = t;
        slot_of[2 * t + k] = idx;
    }
}

// ==================================================================================
// GEMM1: depth-2 counted-vmcnt pipeline, 3 LDS buffers, chunked-8 XCD swizzle
// ==================================================================================
__global__ __launch_bounds__(256) void gemm1_kernel(
    const unsigned short* __restrict__ xb, const unsigned short* __restrict__ W1T,
    const float* __restrict__ b1f, const int* __restrict__ tok_list,
    const int* __restrict__ offs, const int* __restrict__ cnt,
    unsigned short* __restrict__ act) {
    const int H = blockIdx.x + 32 * (blockIdx.y + 32 * blockIdx.z);
    const int L = swz_bid(H);
    const int bx = L & 31, by = (L >> 5) & 31, e = L >> 10;
    const int ne = cnt[e];
    if (by * 128 >= ne) return;
    const int off_e = offs[e];
    __shared__ unsigned short Asm[3][128 * 32];
    __shared__ unsigned short Bsm[3][128 * 32];
    __shared__ int toks[128];
    const int tid = threadIdx.x, w = tid >> 6, lane = tid & 63;
    if (tid < 128) {
        int r = by * 128 + tid;
        toks[tid] = tok_list[off_e + (r < ne ? r : ne - 1)];
    }
    __syncthreads();
    const int arow0 = w * 16 + (lane >> 2);
    const int s_sw = (lane >> 3) & 3;                       // = (arow0>>1)&3
    const int acol = (((lane & 3) ^ s_sw) * 8);
    const int tok0 = toks[arow0], tok1 = toks[arow0 + 64];
    const unsigned short* gA0 = xb + (size_t)tok0 * DM + acol;
    const unsigned short* gA1 = xb + (size_t)tok1 * DM + acol;
    const unsigned short* Wte = W1T + (size_t)e * DF * DM;
    const unsigned short* gB0 = Wte + (size_t)(bx * 128 + arow0) * DM + acol;
    const unsigned short* gB1 = gB0 + (size_t)64 * DM;
    f32x4 acc[4][4] = {};
    const int mb = (w >> 1) * 64, nb = (w & 1) * 64;
    const int rdoff = (((lane >> 4) ^ ((lane >> 1) & 3)) * 8);

#define STAGE1(buf, kk) do { \
        load_lds16(gA0 + (kk), &Asm[buf][(w) * 16 * 32]); \
        load_lds16(gA1 + (kk), &Asm[buf][(w + 4) * 16 * 32]); \
        load_lds16(gB0 + (kk), &Bsm[buf][(w) * 16 * 32]); \
        load_lds16(gB1 + (kk), &Bsm[buf][(w + 4) * 16 * 32]); \
    } while (0)

    STAGE1(0, 0);
    STAGE1(1, 32);
    const int NK = DM / 32;          // 32
    int cur = 0, nxt = 2;
    for (int t = 0; t < NK; ++t) {
        if (t + 1 < NK) { asm volatile("s_waitcnt vmcnt(4)" ::: "memory"); }
        else            { asm volatile("s_waitcnt vmcnt(0)" ::: "memory"); }
        __builtin_amdgcn_s_barrier();
        if (t + 2 < NK) STAGE1(nxt, (t + 2) * 32);
        const unsigned short* As = &Asm[cur][0];
        const unsigned short* Bs = &Bsm[cur][0];
        bf16x8 af[4], bfv[4];
#pragma unroll
        for (int i = 0; i < 4; i++)
            af[i] = *(const bf16x8*)&As[(mb + i * 16 + (lane & 15)) * 32 + rdoff];
#pragma unroll
        for (int j = 0; j < 4; j++)
            bfv[j] = *(const bf16x8*)&Bs[(nb + j * 16 + (lane & 15)) * 32 + rdoff];
        __builtin_amdgcn_s_setprio(1);
#pragma unroll
        for (int i = 0; i < 4; i++)
#pragma unroll
            for (int j = 0; j < 4; j++)
                acc[i][j] = __builtin_amdgcn_mfma_f32_16x16x32_bf16(af[i], bfv[j], acc[i][j], 0, 0, 0);
        __builtin_amdgcn_s_setprio(0);
        cur = (cur == 2) ? 0 : cur + 1;
        nxt = (nxt == 2) ? 0 : nxt + 1;
    }
#undef STAGE1

    const bool even_e = (e & 1) == 0;
    const float* b1e = b1f + (size_t)e * DF + bx * 128;
#pragma unroll
    for (int i = 0; i < 4; i++) {
#pragma unroll
        for (int r = 0; r < 4; r++) {
            int m = mb + i * 16 + ((lane >> 4) * 4) + r;
            int grow = by * 128 + m;
            if (grow < ne) {
                unsigned short* dst = act + (size_t)(off_e + grow) * DF + bx * 128;
#pragma unroll
                for (int j = 0; j < 4; j++) {
                    int n = nb + j * 16 + (lane & 15);
                    float h = acc[i][j][r] + b1e[n];
                    float a = even_e ? gelu_f(h) : silu_f(h);
                    dst[n] = f2b(a);
                }
            }
        }
    }
}

// ==================================================================================
// GEMM2: same pipeline + swizzle
// ==================================================================================
__global__ __launch_bounds__(256) void gemm2_kernel(
    const unsigned short* __restrict__ act, const unsigned short* __restrict__ W2T,
    const float* __restrict__ b2f, const int* __restrict__ offs,
    const int* __restrict__ cnt, float* __restrict__ yall) {
    const int H = blockIdx.x + 8 * (blockIdx.y + 32 * blockIdx.z);
    const int L = swz_bid(H);
    const int bx = L & 7, by = (L >> 3) & 31, e = L >> 8;
    const int ne = cnt[e];
    if (by * 128 >= ne) return;
    const int off_e = offs[e];
    __shared__ unsigned short Asm[3][128 * 32];
    __shared__ unsigned short Bsm[3][128 * 32];
    const int tid = threadIdx.x, w = tid >> 6, lane = tid & 63;
    const int arow0 = w * 16 + (lane >> 2);
    const int s_sw = (lane >> 3) & 3;
    const int acol = (((lane & 3) ^ s_sw) * 8);
    int r0 = by * 128 + arow0;       if (r0 > ne - 1) r0 = ne - 1;
    int r1 = by * 128 + arow0 + 64;  if (r1 > ne - 1) r1 = ne - 1;
    const unsigned short* gA0 = act + (size_t)(off_e + r0) * DF + acol;
    const unsigned short* gA1 = act + (size_t)(off_e + r1) * DF + acol;
    const unsigned short* Wte = W2T + (size_t)e * DM * DF;
    const unsigned short* gB0 = Wte + (size_t)(bx * 128 + arow0) * DF + acol;
    const unsigned short* gB1 = gB0 + (size_t)64 * DF;
    f32x4 acc[4][4] = {};
    const int mb = (w >> 1) * 64, nb = (w & 1) * 64;
    const int rdoff = (((lane >> 4) ^ ((lane >> 1) & 3)) * 8);

#define STAGE2(buf, kk) do { \
        load_lds16(gA0 + (kk), &Asm[buf][(w) * 16 * 32]); \
        load_lds16(gA1 + (kk), &Asm[buf][(w + 4) * 16 * 32]); \
        load_lds16(gB0 + (kk), &Bsm[buf][(w) * 16 * 32]); \
        load_lds16(gB1 + (kk), &Bsm[buf][(w + 4) * 16 * 32]); \
    } while (0)

    STAGE2(0, 0);
    STAGE2(1, 32);
    const int NK = DF / 32;          // 128
    int cur = 0, nxt = 2;
    for (int t = 0; t < NK; ++t) {
        if (t + 1 < NK) { asm volatile("s_waitcnt vmcnt(4)" ::: "memory"); }
        else            { asm volatile("s_waitcnt vmcnt(0)" ::: "memory"); }
        __builtin_amdgcn_s_barrier();
        if (t + 2 < NK) STAGE2(nxt, (t + 2) * 32);
        const unsigned short* As = &Asm[cur][0];
        const unsigned short* Bs = &Bsm[cur][0];
        bf16x8 af[4], bfv[4];
#pragma unroll
        for (int i = 0; i < 4; i++)
            af[i] = *(const bf16x8*)&As[(mb + i * 16 + (lane & 15)) * 32 + rdoff];
#pragma unroll
        for (int j = 0; j < 4; j++)
            bfv[j] = *(const bf16x8*)&Bs[(nb + j * 16 + (lane & 15)) * 32 + rdoff];
        __builtin_amdgcn_s_setprio(1);
#pragma unroll
        for (int i = 0; i < 4; i++)
#pragma unroll
            for (int j = 0; j < 4; j++)
                acc[i][j] = __builtin_amdgcn_mfma_f32_16x16x32_bf16(af[i], bfv[j], acc[i][j], 0, 0, 0);
        __builtin_amdgcn_s_setprio(0);
        cur = (cur == 2) ? 0 : cur + 1;
        nxt = (nxt == 2) ? 0 : nxt + 1;
    }
#undef STAGE2

    const float* b2e = b2f + (size_t)e * DM + bx * 128;
#pragma unroll
    for (int i = 0; i < 4; i++) {
#pragma unroll
        for (int r = 0; r < 4; r++) {
            int m = mb + i * 16 + ((lane >> 4) * 4) + r;
            int grow = by * 128 + m;
            if (grow < ne) {
                float* dst = yall + (size_t)(off_e + grow) * DM + bx * 128;
#pragma unroll
                for (int j = 0; j < 4; j++) {
                    int n = nb + j * 16 + (lane & 15);
                    dst[n] = acc[i][j][r] + b2e[n];
                }
            }
        }
    }
}

// ---------------- combine ----------------
__global__ __launch_bounds__(256) void combine_kernel(
    const float* __restrict__ yall, const int* __restrict__ slot_of,
    const float* __restrict__ tok_s, void* __restrict__ out, const int* __restrict__ flag) {
    const int t = blockIdx.x;
    const int c = threadIdx.x * 4;
    const int s0i = slot_of[2 * t], s1i = slot_of[2 * t + 1];
    const float w0 = tok_s[2 * t], w1 = tok_s[2 * t + 1];
    float4 a = *(const float4*)&yall[(size_t)s0i * DM + c];
    float4 b = *(const float4*)&yall[(size_t)s1i * DM + c];
    float4 r;
    r.x = w0 * a.x + w1 * b.x;
    r.y = w0 * a.y + w1 * b.y;
    r.z = w0 * a.z + w1 * b.z;
    r.w = w0 * a.w + w1 * b.w;
    if (*flag) {
        *(float4*)((float*)out + (size_t)t * DM + c) = r;
    } else {
        ushort4 o;
        o.x = f2b(r.x); o.y = f2b(r.y); o.z = f2b(r.z); o.w = f2b(r.w);
        *(ushort4*)((unsigned short*)out + (size_t)t * DM + c) = o;
    }
}

extern "C" void kernel_launch(void* const* d_in, const int* in_sizes, int n_in,
                              void* d_out, int out_size, void* d_ws, size_t ws_size,
                              hipStream_t stream) {
    (void)in_sizes; (void)n_in; (void)out_size; (void)ws_size;
    const void* x  = d_in[0];
    const void* W1 = d_in[1];
    const void* b1 = d_in[2];
    const void* W2 = d_in[3];
    const void* b2 = d_in[4];
    const void* Wg = d_in[5];
    const void* bg = d_in[6];

    uint8_t* wsb = (uint8_t*)d_ws;
    int* ip = (int*)wsb;
    int* flag  = ip;          // [0]
    int* cnt   = ip + 8;      // [8]
    int* cnt2  = ip + 16;     // [8]
    int* offs  = ip + 24;     // [8]
    int* tok_e = ip + 32;     // [2T]
    float* tok_s  = (float*)(tok_e + 2 * T_TOK);
    int* tok_list = (int*)(tok_s + 2 * T_TOK);
    int* slot_of  = tok_list + 2 * T_TOK;
    size_t head = (size_t)((uint8_t*)(slot_of + 2 * T_TOK) - wsb);
    head = (head + 255) & ~(size_t)255;
    float* b1f = (float*)(wsb + head);
    float* b2f = b1f + (size_t)NE * DF;
    unsigned short* xb  = (unsigned short*)(b2f + (size_t)NE * DM);
    unsigned short* W1T = xb + (size_t)T_TOK * DM;
    unsigned short* W2T = W1T + (size_t)NE * DM * DF;
    unsigned short* actb = W2T + (size_t)NE * DM * DF;
    float* yall = (float*)W1T;   // overlay: W1T dead after gemm1, yall written by gemm2

    hipMemsetAsync(ip, 0, 128, stream);   // zero flag + cnt + cnt2
    detect_kernel<<<256, 256, 0, stream>>>((const unsigned short*)x, flag);
    convx_kernel<<<(T_TOK * DM) / 2048, 256, 0, stream>>>(x, flag, xb);
    convf_kernel<<<(NE * (DF + DM)) / 256, 256, 0, stream>>>(b1, b2, flag, b1f, b2f);
    transpose_kernel<<<dim3(64, 16, 16), 256, 0, stream>>>(W1, W2, W1T, W2T, flag);
    gate_kernel<<<T_TOK / 4, 256, 0, stream>>>(x, Wg, bg, flag, cnt, tok_e, tok_s);
    scan_kernel<<<1, 64, 0, stream>>>(cnt, offs);
    place_kernel<<<T_TOK / 256, 256, 0, stream>>>(tok_e, offs, cnt2, tok_list, slot_of);
    gemm1_kernel<<<dim3(DF / 128, T_TOK / 128, NE), 256, 0, stream>>>(xb, W1T, b1f, tok_list, offs, cnt, actb);
    gemm2_kernel<<<dim3(DM / 128, T_TOK / 128, NE), 256, 0, stream>>>(actb, W2T, b2f, offs, cnt, yall);
    combine_kernel<<<T_TOK, 256, 0, stream>>>(yall, slot_of, tok_s, d_out, flag);
}

// Round 3
// 715.715 us; speedup vs baseline: 1.0586x; 1.0586x over previous
//
#include <hip/hip_runtime.h>
#include <stdint.h>

#define T_TOK 4096
#define DM 1024
#define DF 4096
#define NE 8

typedef __attribute__((ext_vector_type(8))) short bf16x8;
typedef __attribute__((ext_vector_type(4))) float f32x4;

__device__ __forceinline__ float b2f(unsigned short u) {
    union { unsigned int i; float f; } v; v.i = ((unsigned int)u) << 16; return v.f;
}
__device__ __forceinline__ unsigned short f2b(float f) {
    unsigned int i = __float_as_uint(f);
    unsigned int r = (i + 0x7FFFu + ((i >> 16) & 1u)) >> 16;
    return (unsigned short)r;
}
__device__ __forceinline__ void load_lds16(const void* g, void* l) {
    __builtin_amdgcn_global_load_lds((__attribute__((address_space(1))) void*)(g),
                                     (__attribute__((address_space(3))) void*)(l), 16, 0, 0);
}

__device__ __forceinline__ float fexp2(float x) {
#if __has_builtin(__builtin_amdgcn_exp2f)
    return __builtin_amdgcn_exp2f(x);
#else
    return exp2f(x);
#endif
}
__device__ __forceinline__ float frcp(float x) {
#if __has_builtin(__builtin_amdgcn_rcpf)
    return __builtin_amdgcn_rcpf(x);
#else
    return 1.0f / x;
#endif
}

// exact-erf GELU via A&S 7.1.26 (|erf err| <= 1.5e-7, far below bf16 noise)
__device__ __forceinline__ float gelu_f(float h) {
    float z = h * 0.70710678118654752f;
    float az = fabsf(z);
    float t = frcp(1.0f + 0.3275911f * az);
    float p = ((((1.061405429f * t - 1.453152027f) * t + 1.421413741f) * t
                - 0.284496736f) * t + 0.254829592f) * t;
    float e = fexp2(-1.4426950408889634f * az * az);
    float er = 1.0f - p * e;
    er = (z < 0.f) ? -er : er;
    return 0.5f * h * (1.0f + er);
}
__device__ __forceinline__ float silu_f(float h) {
    return h * frcp(1.0f + fexp2(-1.4426950408889634f * h));
}

// ---------------- dtype detector ----------------
__global__ __launch_bounds__(256) void detect_kernel(const unsigned short* __restrict__ xu,
                                                     int* __restrict__ flag) {
    const int i = (blockIdx.x * 256 + threadIdx.x) * 4;
    uint2 v = *(const uint2*)&xu[i];
    unsigned int a = v.x, b = v.y;
    int found = 0;
    if (((a >> 7)  & 0xFF) == 0xFF) found = 1;
    if (((a >> 23) & 0xFF) == 0xFF) found = 1;
    if (((b >> 7)  & 0xFF) == 0xFF) found = 1;
    if (((b >> 23) & 0xFF) == 0xFF) found = 1;
    if (__ballot(found) != 0 && (threadIdx.x & 63) == 0) atomicOr(flag, 1);
}

// ---------------- x -> bf16 (cast or copy) ----------------
__global__ __launch_bounds__(256) void convx_kernel(const void* __restrict__ xin,
                                                    const int* __restrict__ flag,
                                                    unsigned short* __restrict__ xb) {
    const size_t i = ((size_t)blockIdx.x * 256 + threadIdx.x) * 8;
    if (*flag) {
        const float* xf = (const float*)xin + i;
        float4 a = *(const float4*)xf;
        float4 b = *(const float4*)(xf + 4);
        alignas(16) unsigned short t[8] = { f2b(a.x), f2b(a.y), f2b(a.z), f2b(a.w),
                                            f2b(b.x), f2b(b.y), f2b(b.z), f2b(b.w) };
        *(uint4*)(xb + i) = *(const uint4*)t;
    } else {
        *(uint4*)(xb + i) = *(const uint4*)((const unsigned short*)xin + i);
    }
}

// ---------------- b1 + b2 -> fp32 (one launch) ----------------
__global__ void convf_kernel(const void* __restrict__ b1, const void* __restrict__ b2,
                             const int* __restrict__ flag,
                             float* __restrict__ d1, float* __restrict__ d2) {
    const int i = blockIdx.x * 256 + threadIdx.x;
    const int isf = *flag;
    if (i < NE * DF) {
        d1[i] = isf ? ((const float*)b1)[i] : b2f(((const unsigned short*)b1)[i]);
    } else {
        int j = i - NE * DF;
        d2[j] = isf ? ((const float*)b2)[j] : b2f(((const unsigned short*)b2)[j]);
    }
}

// ---------------- W1 and W2 transpose+cast in ONE launch ----------------
__global__ __launch_bounds__(256) void transpose_kernel(
    const void* __restrict__ in1, const void* __restrict__ in2,
    unsigned short* __restrict__ out1, unsigned short* __restrict__ out2,
    const int* __restrict__ flag) {
    __shared__ unsigned short tile[64][65];
    const int isf = *flag;
    const void* in; unsigned short* out;
    int R, C, rt, ct; size_t base;
    if (blockIdx.z < 8) {
        in = in1; out = out1; R = DM; C = DF;
        base = (size_t)blockIdx.z * R * C;
        rt = blockIdx.y; ct = blockIdx.x;                 // 16 x 64 tiles
    } else {
        in = in2; out = out2; R = DF; C = DM;
        base = (size_t)(blockIdx.z - 8) * R * C;
        ct = blockIdx.x & 15;                              // 64 x 16 tiles
        rt = (blockIdx.y << 2) | (blockIdx.x >> 4);
    }
    const int r0 = rt * 64, c0 = ct * 64;
    const int lr = threadIdx.x >> 2;
    const int lc = (threadIdx.x & 3) * 16;
    if (isf) {
        const float* src = (const float*)in + base + (size_t)(r0 + lr) * C + c0 + lc;
#pragma unroll
        for (int q = 0; q < 4; q++) {
            float4 v = *(const float4*)(src + q * 4);
            tile[lr][lc + q * 4 + 0] = f2b(v.x);
            tile[lr][lc + q * 4 + 1] = f2b(v.y);
            tile[lr][lc + q * 4 + 2] = f2b(v.z);
            tile[lr][lc + q * 4 + 3] = f2b(v.w);
        }
    } else {
        const unsigned short* src = (const unsigned short*)in + base + (size_t)(r0 + lr) * C + c0 + lc;
#pragma unroll
        for (int q = 0; q < 2; q++) {
            uint4 v = *(const uint4*)(src + q * 8);
            unsigned int w[4] = { v.x, v.y, v.z, v.w };
#pragma unroll
            for (int j = 0; j < 4; j++) {
                tile[lr][lc + q * 8 + 2 * j]     = (unsigned short)(w[j] & 0xffff);
                tile[lr][lc + q * 8 + 2 * j + 1] = (unsigned short)(w[j] >> 16);
            }
        }
    }
    __syncthreads();
    const int oc = threadIdx.x >> 2;
    const int oj = (threadIdx.x & 3) * 16;
    alignas(16) unsigned short tmp[16];
#pragma unroll
    for (int j = 0; j < 16; j++) tmp[j] = tile[oj + j][oc];
    unsigned short* dst = out + base + (size_t)(c0 + oc) * R + r0 + oj;
    *(uint4*)(dst) = *(const uint4*)(tmp);
    *(uint4*)(dst + 8) = *(const uint4*)(tmp + 8);
}

// ---------------- gate: one wave per token, NO atomics ----------------
__global__ __launch_bounds__(256) void gate_kernel(
    const void* __restrict__ x, const void* __restrict__ Wg, const void* __restrict__ bg,
    const int* __restrict__ flag,
    int* __restrict__ tok_e, float* __restrict__ tok_s) {
    const int isf = *flag;
    const int wave = threadIdx.x >> 6, lane = threadIdx.x & 63;
    const int t = blockIdx.x * 4 + wave;
    float p[8] = {0.f,0.f,0.f,0.f,0.f,0.f,0.f,0.f};
    if (isf) {
        const float* xr = (const float*)x + (size_t)t * DM;
        const float* wg = (const float*)Wg;
        for (int i = lane; i < DM; i += 64) {
            float xv = xr[i];
            float4 a = *(const float4*)(wg + (size_t)i * 8);
            float4 b = *(const float4*)(wg + (size_t)i * 8 + 4);
            p[0] += xv * a.x; p[1] += xv * a.y; p[2] += xv * a.z; p[3] += xv * a.w;
            p[4] += xv * b.x; p[5] += xv * b.y; p[6] += xv * b.z; p[7] += xv * b.w;
        }
    } else {
        const unsigned short* xr = (const unsigned short*)x + (size_t)t * DM;
        const unsigned short* wg = (const unsigned short*)Wg;
        for (int i = lane; i < DM; i += 64) {
            float xv = b2f(xr[i]);
            uint4 wv = *(const uint4*)(wg + (size_t)i * 8);
            p[0] += xv * b2f((unsigned short)(wv.x & 0xffff));
            p[1] += xv * b2f((unsigned short)(wv.x >> 16));
            p[2] += xv * b2f((unsigned short)(wv.y & 0xffff));
            p[3] += xv * b2f((unsigned short)(wv.y >> 16));
            p[4] += xv * b2f((unsigned short)(wv.z & 0xffff));
            p[5] += xv * b2f((unsigned short)(wv.z >> 16));
            p[6] += xv * b2f((unsigned short)(wv.w & 0xffff));
            p[7] += xv * b2f((unsigned short)(wv.w >> 16));
        }
    }
    for (int off = 32; off > 0; off >>= 1)
        for (int e = 0; e < 8; e++) p[e] += __shfl_down(p[e], off);
    if (lane == 0) {
        for (int e = 0; e < 8; e++)
            p[e] += isf ? ((const float*)bg)[e] : b2f(((const unsigned short*)bg)[e]);
        int e0 = 0;
        for (int e = 1; e < 8; e++) if (p[e] > p[e0]) e0 = e;
        int e1 = (e0 == 0) ? 1 : 0;
        for (int e = 0; e < 8; e++) if (e != e0 && p[e] > p[e1]) e1 = e;
        float z = expf(p[e1] - p[e0]);
        float s0 = 1.f / (1.f + z);
        tok_e[2 * t] = e0; tok_e[2 * t + 1] = e1;
        tok_s[2 * t] = s0; tok_s[2 * t + 1] = z * s0;
    }
}

// ---------------- histogram + scan: one block, register counters, no atomics ----------------
__global__ __launch_bounds__(256) void histscan_kernel(const int* __restrict__ tok_e,
                                                       int* __restrict__ cnt,
                                                       int* __restrict__ offs) {
    const int tid = threadIdx.x, w = tid >> 6, lane = tid & 63;
    int c[8] = {0,0,0,0,0,0,0,0};
    for (int i = tid; i < 2 * T_TOK; i += 256) {
        int v = tok_e[i];
#pragma unroll
        for (int e = 0; e < 8; e++) c[e] += (v == e);
    }
    for (int off = 32; off > 0; off >>= 1)
#pragma unroll
        for (int e = 0; e < 8; e++) c[e] += __shfl_down(c[e], off);
    __shared__ int ws[4][8];
    if (lane == 0)
#pragma unroll
        for (int e = 0; e < 8; e++) ws[w][e] = c[e];
    __syncthreads();
    if (tid == 0) {
        int s = 0;
        for (int e = 0; e < 8; e++) {
            int t = ws[0][e] + ws[1][e] + ws[2][e] + ws[3][e];
            cnt[e] = t; offs[e] = s; s += t;
        }
    }
}

// ---------------- deterministic ordered compaction: one block per expert, no atomics ----------------
__global__ __launch_bounds__(256) void compact_kernel(const int* __restrict__ tok_e,
                                                      const int* __restrict__ offs,
                                                      int* __restrict__ tok_list,
                                                      int* __restrict__ slot_of) {
    const int e = blockIdx.x;
    const int tid = threadIdx.x, w = tid >> 6, lane = tid & 63;
    __shared__ int wtot[4];
    __shared__ int running;
    if (tid == 0) running = 0;
    __syncthreads();
    const int base = offs[e];
    for (int i0 = 0; i0 < 2 * T_TOK; i0 += 256) {
        const int i = i0 + tid;
        const int v = tok_e[i];
        const bool pred = (v == e);
        unsigned long long m = __ballot(pred);
        int rank = __popcll(m & ((1ull << lane) - 1ull));
        if (lane == 0) wtot[w] = __popcll(m);
        __syncthreads();
        int woff = 0;
        for (int ww = 0; ww < w; ww++) woff += wtot[ww];
        const int tot = wtot[0] + wtot[1] + wtot[2] + wtot[3];
        const int r = running;
        if (pred) {
            int pos = base + r + woff + rank;
            tok_list[pos] = i >> 1;
            slot_of[i] = pos;
        }
        __syncthreads();
        if (tid == 0) running += tot;
        __syncthreads();
    }
}

// ==================================================================================
// GEMM1: depth-2 counted-vmcnt, 3 LDS buffers, loop UNROLLED x3 (compile-time bufs)
// ==================================================================================
__global__ __launch_bounds__(256) void gemm1_kernel(
    const unsigned short* __restrict__ xb, const unsigned short* __restrict__ W1T,
    const float* __restrict__ b1f, const int* __restrict__ tok_list,
    const int* __restrict__ offs, const int* __restrict__ cnt,
    unsigned short* __restrict__ act) {
    const int e = blockIdx.z, by = blockIdx.y, bx = blockIdx.x;
    const int ne = cnt[e];
    if (by * 128 >= ne) return;
    const int off_e = offs[e];
    __shared__ unsigned short Asm[3][128 * 32];
    __shared__ unsigned short Bsm[3][128 * 32];
    __shared__ int toks[128];
    const int tid = threadIdx.x, w = tid >> 6, lane = tid & 63;
    if (tid < 128) {
        int r = by * 128 + tid;
        toks[tid] = tok_list[off_e + (r < ne ? r : ne - 1)];
    }
    __syncthreads();
    const int arow0 = w * 16 + (lane >> 2);
    const int s_sw = (lane >> 3) & 3;                       // = (arow0>>1)&3
    const int acol = (((lane & 3) ^ s_sw) * 8);
    const int tok0 = toks[arow0], tok1 = toks[arow0 + 64];
    const unsigned short* gA0 = xb + (size_t)tok0 * DM + acol;
    const unsigned short* gA1 = xb + (size_t)tok1 * DM + acol;
    const unsigned short* Wte = W1T + (size_t)e * DF * DM;
    const unsigned short* gB0 = Wte + (size_t)(bx * 128 + arow0) * DM + acol;
    const unsigned short* gB1 = gB0 + (size_t)64 * DM;
    f32x4 acc[4][4] = {};
    const int mb = (w >> 1) * 64, nb = (w & 1) * 64;
    const int rdoff = (((lane >> 4) ^ ((lane >> 1) & 3)) * 8);

#define STAGE1(buf, kk) do { \
        load_lds16(gA0 + (kk), &Asm[buf][(w) * 16 * 32]); \
        load_lds16(gA1 + (kk), &Asm[buf][(w + 4) * 16 * 32]); \
        load_lds16(gB0 + (kk), &Bsm[buf][(w) * 16 * 32]); \
        load_lds16(gB1 + (kk), &Bsm[buf][(w + 4) * 16 * 32]); \
    } while (0)

#define GBODY1(W, DOSTAGE, p, s, kk) do { \
        asm volatile("s_waitcnt vmcnt(" #W ")" ::: "memory"); \
        __builtin_amdgcn_s_barrier(); \
        if (DOSTAGE) { STAGE1(s, kk); } \
        bf16x8 af[4], bfv[4]; \
        _Pragma("unroll") \
        for (int i = 0; i < 4; i++) \
            af[i] = *(const bf16x8*)&Asm[p][(mb + i * 16 + (lane & 15)) * 32 + rdoff]; \
        _Pragma("unroll") \
        for (int j = 0; j < 4; j++) \
            bfv[j] = *(const bf16x8*)&Bsm[p][(nb + j * 16 + (lane & 15)) * 32 + rdoff]; \
        __builtin_amdgcn_s_setprio(1); \
        _Pragma("unroll") \
        for (int i = 0; i < 4; i++) \
            _Pragma("unroll") \
            for (int j = 0; j < 4; j++) \
                acc[i][j] = __builtin_amdgcn_mfma_f32_16x16x32_bf16(af[i], bfv[j], acc[i][j], 0, 0, 0); \
        __builtin_amdgcn_s_setprio(0); \
    } while (0)

    STAGE1(0, 0);
    STAGE1(1, 32);
    for (int t3 = 0; t3 < 30; t3 += 3) {           // t = 0..29, NK = 32
        const int kb = t3 * 32;
        GBODY1(4, true, 0, 2, kb + 64);
        GBODY1(4, true, 1, 0, kb + 96);
        GBODY1(4, true, 2, 1, kb + 128);
    }
    GBODY1(4, false, 0, 0, 0);                     // t = 30
    GBODY1(0, false, 1, 0, 0);                     // t = 31
#undef GBODY1
#undef STAGE1

    const bool even_e = (e & 1) == 0;
    const float* b1e = b1f + (size_t)e * DF + bx * 128;
#pragma unroll
    for (int i = 0; i < 4; i++) {
#pragma unroll
        for (int r = 0; r < 4; r++) {
            int m = mb + i * 16 + ((lane >> 4) * 4) + r;
            int grow = by * 128 + m;
            if (grow < ne) {
                unsigned short* dst = act + (size_t)(off_e + grow) * DF + bx * 128;
#pragma unroll
                for (int j = 0; j < 4; j++) {
                    int n = nb + j * 16 + (lane & 15);
                    float h = acc[i][j][r] + b1e[n];
                    float a = even_e ? gelu_f(h) : silu_f(h);
                    dst[n] = f2b(a);
                }
            }
        }
    }
}

// ==================================================================================
// GEMM2: same pipeline, NK = 128
// ==================================================================================
__global__ __launch_bounds__(256) void gemm2_kernel(
    const unsigned short* __restrict__ act, const unsigned short* __restrict__ W2T,
    const float* __restrict__ b2f, const int* __restrict__ offs,
    const int* __restrict__ cnt, float* __restrict__ yall) {
    const int e = blockIdx.z, by = blockIdx.y, bx = blockIdx.x;
    const int ne = cnt[e];
    if (by * 128 >= ne) return;
    const int off_e = offs[e];
    __shared__ unsigned short Asm[3][128 * 32];
    __shared__ unsigned short Bsm[3][128 * 32];
    const int tid = threadIdx.x, w = tid >> 6, lane = tid & 63;
    const int arow0 = w * 16 + (lane >> 2);
    const int s_sw = (lane >> 3) & 3;
    const int acol = (((lane & 3) ^ s_sw) * 8);
    int r0 = by * 128 + arow0;       if (r0 > ne - 1) r0 = ne - 1;
    int r1 = by * 128 + arow0 + 64;  if (r1 > ne - 1) r1 = ne - 1;
    const unsigned short* gA0 = act + (size_t)(off_e + r0) * DF + acol;
    const unsigned short* gA1 = act + (size_t)(off_e + r1) * DF + acol;
    const unsigned short* Wte = W2T + (size_t)e * DM * DF;
    const unsigned short* gB0 = Wte + (size_t)(bx * 128 + arow0) * DF + acol;
    const unsigned short* gB1 = gB0 + (size_t)64 * DF;
    f32x4 acc[4][4] = {};
    const int mb = (w >> 1) * 64, nb = (w & 1) * 64;
    const int rdoff = (((lane >> 4) ^ ((lane >> 1) & 3)) * 8);

#define STAGE2(buf, kk) do { \
        load_lds16(gA0 + (kk), &Asm[buf][(w) * 16 * 32]); \
        load_lds16(gA1 + (kk), &Asm[buf][(w + 4) * 16 * 32]); \
        load_lds16(gB0 + (kk), &Bsm[buf][(w) * 16 * 32]); \
        load_lds16(gB1 + (kk), &Bsm[buf][(w + 4) * 16 * 32]); \
    } while (0)

#define GBODY2(W, DOSTAGE, p, s, kk) do { \
        asm volatile("s_waitcnt vmcnt(" #W ")" ::: "memory"); \
        __builtin_amdgcn_s_barrier(); \
        if (DOSTAGE) { STAGE2(s, kk); } \
        bf16x8 af[4], bfv[4]; \
        _Pragma("unroll") \
        for (int i = 0; i < 4; i++) \
            af[i] = *(const bf16x8*)&Asm[p][(mb + i * 16 + (lane & 15)) * 32 + rdoff]; \
        _Pragma("unroll") \
        for (int j = 0; j < 4; j++) \
            bfv[j] = *(const bf16x8*)&Bsm[p][(nb + j * 16 + (lane & 15)) * 32 + rdoff]; \
        __builtin_amdgcn_s_setprio(1); \
        _Pragma("unroll") \
        for (int i = 0; i < 4; i++) \
            _Pragma("unroll") \
            for (int j = 0; j < 4; j++) \
                acc[i][j] = __builtin_amdgcn_mfma_f32_16x16x32_bf16(af[i], bfv[j], acc[i][j], 0, 0, 0); \
        __builtin_amdgcn_s_setprio(0); \
    } while (0)

    STAGE2(0, 0);
    STAGE2(1, 32);
    for (int t3 = 0; t3 < 126; t3 += 3) {          // t = 0..125, NK = 128
        const int kb = t3 * 32;
        GBODY2(4, true, 0, 2, kb + 64);
        GBODY2(4, true, 1, 0, kb + 96);
        GBODY2(4, true, 2, 1, kb + 128);
    }
    GBODY2(4, false, 0, 0, 0);                     // t = 126
    GBODY2(0, false, 1, 0, 0);                     // t = 127
#undef GBODY2
#undef STAGE2

    const float* b2e = b2f + (size_t)e * DM + bx * 128;
#pragma unroll
    for (int i = 0; i < 4; i++) {
#pragma unroll
        for (int r = 0; r < 4; r++) {
            int m = mb + i * 16 + ((lane >> 4) * 4) + r;
            int grow = by * 128 + m;
            if (grow < ne) {
                float* dst = yall + (size_t)(off_e + grow) * DM + bx * 128;
#pragma unroll
                for (int j = 0; j < 4; j++) {
                    int n = nb + j * 16 + (lane & 15);
                    dst[n] = acc[i][j][r] + b2e[n];
                }
            }
        }
    }
}

// ---------------- combine ----------------
__global__ __launch_bounds__(256) void combine_kernel(
    const float* __restrict__ yall, const int* __restrict__ slot_of,
    const float* __restrict__ tok_s, void* __restrict__ out, const int* __restrict__ flag) {
    const int t = blockIdx.x;
    const int c = threadIdx.x * 4;
    const int s0i = slot_of[2 * t], s1i = slot_of[2 * t + 1];
    const float w0 = tok_s[2 * t], w1 = tok_s[2 * t + 1];
    float4 a = *(const float4*)&yall[(size_t)s0i * DM + c];
    float4 b = *(const float4*)&yall[(size_t)s1i * DM + c];
    float4 r;
    r.x = w0 * a.x + w1 * b.x;
    r.y = w0 * a.y + w1 * b.y;
    r.z = w0 * a.z + w1 * b.z;
    r.w = w0 * a.w + w1 * b.w;
    if (*flag) {
        *(float4*)((float*)out + (size_t)t * DM + c) = r;
    } else {
        ushort4 o;
        o.x = f2b(r.x); o.y = f2b(r.y); o.z = f2b(r.z); o.w = f2b(r.w);
        *(ushort4*)((unsigned short*)out + (size_t)t * DM + c) = o;
    }
}

extern "C" void kernel_launch(void* const* d_in, const int* in_sizes, int n_in,
                              void* d_out, int out_size, void* d_ws, size_t ws_size,
                              hipStream_t stream) {
    (void)in_sizes; (void)n_in; (void)out_size; (void)ws_size;
    const void* x  = d_in[0];
    const void* W1 = d_in[1];
    const void* b1 = d_in[2];
    const void* W2 = d_in[3];
    const void* b2 = d_in[4];
    const void* Wg = d_in[5];
    const void* bg = d_in[6];

    uint8_t* wsb = (uint8_t*)d_ws;
    int* ip = (int*)wsb;
    int* flag  = ip;          // [0]
    int* cnt   = ip + 8;      // [8]
    int* cnt2  = ip + 16;     // [8] (unused, kept for layout stability)
    int* offs  = ip + 24;     // [8]
    int* tok_e = ip + 32;     // [2T]
    float* tok_s  = (float*)(tok_e + 2 * T_TOK);
    int* tok_list = (int*)(tok_s + 2 * T_TOK);
    int* slot_of  = tok_list + 2 * T_TOK;
    size_t head = (size_t)((uint8_t*)(slot_of + 2 * T_TOK) - wsb);
    head = (head + 255) & ~(size_t)255;
    float* b1f = (float*)(wsb + head);
    float* b2f = b1f + (size_t)NE * DF;
    unsigned short* xb  = (unsigned short*)(b2f + (size_t)NE * DM);
    unsigned short* W1T = xb + (size_t)T_TOK * DM;
    unsigned short* W2T = W1T + (size_t)NE * DM * DF;
    unsigned short* actb = W2T + (size_t)NE * DM * DF;
    float* yall = (float*)W1T;   // overlay: W1T dead after gemm1, yall written by gemm2
    (void)cnt2;

    hipMemsetAsync(ip, 0, 128, stream);   // zero flag (+ scratch ints)
    detect_kernel<<<256, 256, 0, stream>>>((const unsigned short*)x, flag);
    convx_kernel<<<(T_TOK * DM) / 2048, 256, 0, stream>>>(x, flag, xb);
    convf_kernel<<<(NE * (DF + DM)) / 256, 256, 0, stream>>>(b1, b2, flag, b1f, b2f);
    transpose_kernel<<<dim3(64, 16, 16), 256, 0, stream>>>(W1, W2, W1T, W2T, flag);
    gate_kernel<<<T_TOK / 4, 256, 0, stream>>>(x, Wg, bg, flag, tok_e, tok_s);
    histscan_kernel<<<1, 256, 0, stream>>>(tok_e, cnt, offs);
    compact_kernel<<<NE, 256, 0, stream>>>(tok_e, offs, tok_list, slot_of);
    gemm1_kernel<<<dim3(DF / 128, T_TOK / 128, NE), 256, 0, stream>>>(xb, W1T, b1f, tok_list, offs, cnt, actb);
    gemm2_kernel<<<dim3(DM / 128, T_TOK / 128, NE), 256, 0, stream>>>(actb, W2T, b2f, offs, cnt, yall);
    combine_kernel<<<T_TOK, 256, 0, stream>>>(yall, slot_of, tok_s, d_out, flag);
}

// Round 4
// 635.183 us; speedup vs baseline: 1.1929x; 1.1268x over previous
//
#include <hip/hip_runtime.h>
#include <stdint.h>

#define T_TOK 4096
#define DM 1024
#define DF 4096
#define NE 8

typedef __attribute__((ext_vector_type(8))) short bf16x8;
typedef __attribute__((ext_vector_type(4))) float f32x4;

__device__ __forceinline__ float b2f(unsigned short u) {
    union { unsigned int i; float f; } v; v.i = ((unsigned int)u) << 16; return v.f;
}
__device__ __forceinline__ unsigned short f2b(float f) {
    unsigned int i = __float_as_uint(f);
    unsigned int r = (i + 0x7FFFu + ((i >> 16) & 1u)) >> 16;
    return (unsigned short)r;
}
__device__ __forceinline__ void load_lds16(const void* g, void* l) {
    __builtin_amdgcn_global_load_lds((__attribute__((address_space(1))) void*)(g),
                                     (__attribute__((address_space(3))) void*)(l), 16, 0, 0);
}

__device__ __forceinline__ float fexp2(float x) {
#if __has_builtin(__builtin_amdgcn_exp2f)
    return __builtin_amdgcn_exp2f(x);
#else
    return exp2f(x);
#endif
}
__device__ __forceinline__ float frcp(float x) {
#if __has_builtin(__builtin_amdgcn_rcpf)
    return __builtin_amdgcn_rcpf(x);
#else
    return 1.0f / x;
#endif
}

// exact-erf GELU via A&S 7.1.26 (|erf err| <= 1.5e-7, far below bf16 noise)
__device__ __forceinline__ float gelu_f(float h) {
    float z = h * 0.70710678118654752f;
    float az = fabsf(z);
    float t = frcp(1.0f + 0.3275911f * az);
    float p = ((((1.061405429f * t - 1.453152027f) * t + 1.421413741f) * t
                - 0.284496736f) * t + 0.254829592f) * t;
    float e = fexp2(-1.4426950408889634f * az * az);
    float er = 1.0f - p * e;
    er = (z < 0.f) ? -er : er;
    return 0.5f * h * (1.0f + er);
}
__device__ __forceinline__ float silu_f(float h) {
    return h * frcp(1.0f + fexp2(-1.4426950408889634f * h));
}

// ---------------- dtype detector ----------------
__global__ __launch_bounds__(256) void detect_kernel(const unsigned short* __restrict__ xu,
                                                     int* __restrict__ flag) {
    const int i = (blockIdx.x * 256 + threadIdx.x) * 4;
    uint2 v = *(const uint2*)&xu[i];
    unsigned int a = v.x, b = v.y;
    int found = 0;
    if (((a >> 7)  & 0xFF) == 0xFF) found = 1;
    if (((a >> 23) & 0xFF) == 0xFF) found = 1;
    if (((b >> 7)  & 0xFF) == 0xFF) found = 1;
    if (((b >> 23) & 0xFF) == 0xFF) found = 1;
    if (__ballot(found) != 0 && (threadIdx.x & 63) == 0) atomicOr(flag, 1);
}

// ---------------- x -> bf16 (cast or copy) ----------------
__global__ __launch_bounds__(256) void convx_kernel(const void* __restrict__ xin,
                                                    const int* __restrict__ flag,
                                                    unsigned short* __restrict__ xb) {
    const size_t i = ((size_t)blockIdx.x * 256 + threadIdx.x) * 8;
    if (*flag) {
        const float* xf = (const float*)xin + i;
        float4 a = *(const float4*)xf;
        float4 b = *(const float4*)(xf + 4);
        alignas(16) unsigned short t[8] = { f2b(a.x), f2b(a.y), f2b(a.z), f2b(a.w),
                                            f2b(b.x), f2b(b.y), f2b(b.z), f2b(b.w) };
        *(uint4*)(xb + i) = *(const uint4*)t;
    } else {
        *(uint4*)(xb + i) = *(const uint4*)((const unsigned short*)xin + i);
    }
}

// ---------------- b1 + b2 -> fp32 (one launch) ----------------
__global__ void convf_kernel(const void* __restrict__ b1, const void* __restrict__ b2,
                             const int* __restrict__ flag,
                             float* __restrict__ d1, float* __restrict__ d2) {
    const int i = blockIdx.x * 256 + threadIdx.x;
    const int isf = *flag;
    if (i < NE * DF) {
        d1[i] = isf ? ((const float*)b1)[i] : b2f(((const unsigned short*)b1)[i]);
    } else {
        int j = i - NE * DF;
        d2[j] = isf ? ((const float*)b2)[j] : b2f(((const unsigned short*)b2)[j]);
    }
}

// ---------------- W1 and W2 transpose+cast in ONE launch ----------------
__global__ __launch_bounds__(256) void transpose_kernel(
    const void* __restrict__ in1, const void* __restrict__ in2,
    unsigned short* __restrict__ out1, unsigned short* __restrict__ out2,
    const int* __restrict__ flag) {
    __shared__ unsigned short tile[64][65];
    const int isf = *flag;
    const void* in; unsigned short* out;
    int R, C, rt, ct; size_t base;
    if (blockIdx.z < 8) {
        in = in1; out = out1; R = DM; C = DF;
        base = (size_t)blockIdx.z * R * C;
        rt = blockIdx.y; ct = blockIdx.x;                 // 16 x 64 tiles
    } else {
        in = in2; out = out2; R = DF; C = DM;
        base = (size_t)(blockIdx.z - 8) * R * C;
        ct = blockIdx.x & 15;                              // 64 x 16 tiles
        rt = (blockIdx.y << 2) | (blockIdx.x >> 4);
    }
    const int r0 = rt * 64, c0 = ct * 64;
    const int lr = threadIdx.x >> 2;
    const int lc = (threadIdx.x & 3) * 16;
    if (isf) {
        const float* src = (const float*)in + base + (size_t)(r0 + lr) * C + c0 + lc;
#pragma unroll
        for (int q = 0; q < 4; q++) {
            float4 v = *(const float4*)(src + q * 4);
            tile[lr][lc + q * 4 + 0] = f2b(v.x);
            tile[lr][lc + q * 4 + 1] = f2b(v.y);
            tile[lr][lc + q * 4 + 2] = f2b(v.z);
            tile[lr][lc + q * 4 + 3] = f2b(v.w);
        }
    } else {
        const unsigned short* src = (const unsigned short*)in + base + (size_t)(r0 + lr) * C + c0 + lc;
#pragma unroll
        for (int q = 0; q < 2; q++) {
            uint4 v = *(const uint4*)(src + q * 8);
            unsigned int w[4] = { v.x, v.y, v.z, v.w };
#pragma unroll
            for (int j = 0; j < 4; j++) {
                tile[lr][lc + q * 8 + 2 * j]     = (unsigned short)(w[j] & 0xffff);
                tile[lr][lc + q * 8 + 2 * j + 1] = (unsigned short)(w[j] >> 16);
            }
        }
    }
    __syncthreads();
    const int oc = threadIdx.x >> 2;
    const int oj = (threadIdx.x & 3) * 16;
    alignas(16) unsigned short tmp[16];
#pragma unroll
    for (int j = 0; j < 16; j++) tmp[j] = tile[oj + j][oc];
    unsigned short* dst = out + base + (size_t)(c0 + oc) * R + r0 + oj;
    *(uint4*)(dst) = *(const uint4*)(tmp);
    *(uint4*)(dst + 8) = *(const uint4*)(tmp + 8);
}

// ---------------- gate: one wave per token, NO atomics ----------------
__global__ __launch_bounds__(256) void gate_kernel(
    const void* __restrict__ x, const void* __restrict__ Wg, const void* __restrict__ bg,
    const int* __restrict__ flag,
    int* __restrict__ tok_e, float* __restrict__ tok_s) {
    const int isf = *flag;
    const int wave = threadIdx.x >> 6, lane = threadIdx.x & 63;
    const int t = blockIdx.x * 4 + wave;
    float p[8] = {0.f,0.f,0.f,0.f,0.f,0.f,0.f,0.f};
    if (isf) {
        const float* xr = (const float*)x + (size_t)t * DM;
        const float* wg = (const float*)Wg;
        for (int i = lane; i < DM; i += 64) {
            float xv = xr[i];
            float4 a = *(const float4*)(wg + (size_t)i * 8);
            float4 b = *(const float4*)(wg + (size_t)i * 8 + 4);
            p[0] += xv * a.x; p[1] += xv * a.y; p[2] += xv * a.z; p[3] += xv * a.w;
            p[4] += xv * b.x; p[5] += xv * b.y; p[6] += xv * b.z; p[7] += xv * b.w;
        }
    } else {
        const unsigned short* xr = (const unsigned short*)x + (size_t)t * DM;
        const unsigned short* wg = (const unsigned short*)Wg;
        for (int i = lane; i < DM; i += 64) {
            float xv = b2f(xr[i]);
            uint4 wv = *(const uint4*)(wg + (size_t)i * 8);
            p[0] += xv * b2f((unsigned short)(wv.x & 0xffff));
            p[1] += xv * b2f((unsigned short)(wv.x >> 16));
            p[2] += xv * b2f((unsigned short)(wv.y & 0xffff));
            p[3] += xv * b2f((unsigned short)(wv.y >> 16));
            p[4] += xv * b2f((unsigned short)(wv.z & 0xffff));
            p[5] += xv * b2f((unsigned short)(wv.z >> 16));
            p[6] += xv * b2f((unsigned short)(wv.w & 0xffff));
            p[7] += xv * b2f((unsigned short)(wv.w >> 16));
        }
    }
    for (int off = 32; off > 0; off >>= 1)
        for (int e = 0; e < 8; e++) p[e] += __shfl_down(p[e], off);
    if (lane == 0) {
        for (int e = 0; e < 8; e++)
            p[e] += isf ? ((const float*)bg)[e] : b2f(((const unsigned short*)bg)[e]);
        int e0 = 0;
        for (int e = 1; e < 8; e++) if (p[e] > p[e0]) e0 = e;
        int e1 = (e0 == 0) ? 1 : 0;
        for (int e = 0; e < 8; e++) if (e != e0 && p[e] > p[e1]) e1 = e;
        float z = expf(p[e1] - p[e0]);
        float s0 = 1.f / (1.f + z);
        tok_e[2 * t] = e0; tok_e[2 * t + 1] = e1;
        tok_s[2 * t] = s0; tok_s[2 * t + 1] = z * s0;
    }
}

// ---------------- compact (with built-in histogram): one block per expert, no atomics ----------------
__global__ __launch_bounds__(256) void compact_kernel(const int* __restrict__ tok_e,
                                                      int* __restrict__ cnt,
                                                      int* __restrict__ offs,
                                                      int* __restrict__ tok_list,
                                                      int* __restrict__ slot_of) {
    const int e = blockIdx.x;
    const int tid = threadIdx.x, w = tid >> 6, lane = tid & 63;
    // pass 1: full histogram (every block computes it; deterministic, no atomics)
    int c[8] = {0,0,0,0,0,0,0,0};
    for (int i = tid; i < 2 * T_TOK; i += 256) {
        int v = tok_e[i];
#pragma unroll
        for (int q = 0; q < 8; q++) c[q] += (v == q);
    }
    for (int off = 32; off > 0; off >>= 1)
#pragma unroll
        for (int q = 0; q < 8; q++) c[q] += __shfl_down(c[q], off);
    __shared__ int ws4[4][8];
    if (lane == 0)
#pragma unroll
        for (int q = 0; q < 8; q++) ws4[w][q] = c[q];
    __syncthreads();
    __shared__ int base_s;
    __shared__ int wtot[4];
    __shared__ int running;
    if (tid == 0) {
        int s = 0, be = 0, ce = 0;
        for (int q = 0; q < 8; q++) {
            int t = ws4[0][q] + ws4[1][q] + ws4[2][q] + ws4[3][q];
            if (q == e) { be = s; ce = t; }
            s += t;
        }
        base_s = be;
        cnt[e] = ce;
        offs[e] = be;
        running = 0;
    }
    __syncthreads();
    const int base = base_s;
    // pass 2: deterministic ordered compaction
    for (int i0 = 0; i0 < 2 * T_TOK; i0 += 256) {
        const int i = i0 + tid;
        const int v = tok_e[i];
        const bool pred = (v == e);
        unsigned long long m = __ballot(pred);
        int rank = __popcll(m & ((1ull << lane) - 1ull));
        if (lane == 0) wtot[w] = __popcll(m);
        __syncthreads();
        int woff = 0;
        for (int ww = 0; ww < w; ww++) woff += wtot[ww];
        const int tot = wtot[0] + wtot[1] + wtot[2] + wtot[3];
        const int r = running;
        if (pred) {
            int pos = base + r + woff + rank;
            tok_list[pos] = i >> 1;
            slot_of[i] = pos;
        }
        __syncthreads();
        if (tid == 0) running += tot;
        __syncthreads();
    }
}

// ==================================================================================
// GEMM1 (round-1 proven structure): 2-buffer, stage-before-compute, one barrier/iter
// ==================================================================================
__global__ __launch_bounds__(256) void gemm1_kernel(
    const unsigned short* __restrict__ xb, const unsigned short* __restrict__ W1T,
    const float* __restrict__ b1f, const int* __restrict__ tok_list,
    const int* __restrict__ offs, const int* __restrict__ cnt,
    unsigned short* __restrict__ act) {
    const int e = blockIdx.z, by = blockIdx.y, bx = blockIdx.x;
    const int ne = cnt[e];
    if (by * 128 >= ne) return;
    const int off_e = offs[e];
    __shared__ unsigned short Asm[2][128 * 32];
    __shared__ unsigned short Bsm[2][128 * 32];
    __shared__ int toks[128];
    const int tid = threadIdx.x, w = tid >> 6, lane = tid & 63;
    if (tid < 128) {
        int r = by * 128 + tid;
        toks[tid] = tok_list[off_e + (r < ne ? r : ne - 1)];
    }
    __syncthreads();
    const int arow0 = w * 16 + (lane >> 2);
    const int s_sw = (lane >> 3) & 3;                       // = (arow0>>1)&3
    const int acol = (((lane & 3) ^ s_sw) * 8);
    const int tok0 = toks[arow0], tok1 = toks[arow0 + 64];
    const unsigned short* gA0 = xb + (size_t)tok0 * DM + acol;
    const unsigned short* gA1 = xb + (size_t)tok1 * DM + acol;
    const unsigned short* Wte = W1T + (size_t)e * DF * DM;
    const unsigned short* gB0 = Wte + (size_t)(bx * 128 + arow0) * DM + acol;
    const unsigned short* gB1 = gB0 + (size_t)64 * DM;
    f32x4 acc[4][4] = {};
    const int mb = (w >> 1) * 64, nb = (w & 1) * 64;
    const int rdoff = (((lane >> 4) ^ ((lane >> 1) & 3)) * 8);

#define STAGE1(buf, kk) do { \
        load_lds16(gA0 + (kk), &Asm[buf][(w) * 16 * 32]); \
        load_lds16(gA1 + (kk), &Asm[buf][(w + 4) * 16 * 32]); \
        load_lds16(gB0 + (kk), &Bsm[buf][(w) * 16 * 32]); \
        load_lds16(gB1 + (kk), &Bsm[buf][(w + 4) * 16 * 32]); \
    } while (0)

    STAGE1(0, 0);
    __syncthreads();
    int cur = 0;
    for (int kk = 0; kk < DM; kk += 32) {
        if (kk + 32 < DM) STAGE1(cur ^ 1, kk + 32);
        bf16x8 af[4], bfv[4];
#pragma unroll
        for (int i = 0; i < 4; i++)
            af[i] = *(const bf16x8*)&Asm[cur][(mb + i * 16 + (lane & 15)) * 32 + rdoff];
#pragma unroll
        for (int j = 0; j < 4; j++)
            bfv[j] = *(const bf16x8*)&Bsm[cur][(nb + j * 16 + (lane & 15)) * 32 + rdoff];
        __builtin_amdgcn_s_setprio(1);
#pragma unroll
        for (int i = 0; i < 4; i++)
#pragma unroll
            for (int j = 0; j < 4; j++)
                acc[i][j] = __builtin_amdgcn_mfma_f32_16x16x32_bf16(af[i], bfv[j], acc[i][j], 0, 0, 0);
        __builtin_amdgcn_s_setprio(0);
        __syncthreads();
        cur ^= 1;
    }
#undef STAGE1

    const bool even_e = (e & 1) == 0;
    const float* b1e = b1f + (size_t)e * DF + bx * 128;
#pragma unroll
    for (int i = 0; i < 4; i++) {
#pragma unroll
        for (int r = 0; r < 4; r++) {
            int m = mb + i * 16 + ((lane >> 4) * 4) + r;
            int grow = by * 128 + m;
            if (grow < ne) {
                unsigned short* dst = act + (size_t)(off_e + grow) * DF + bx * 128;
#pragma unroll
                for (int j = 0; j < 4; j++) {
                    int n = nb + j * 16 + (lane & 15);
                    float h = acc[i][j][r] + b1e[n];
                    float a = even_e ? gelu_f(h) : silu_f(h);
                    dst[n] = f2b(a);
                }
            }
        }
    }
}

// ==================================================================================
// GEMM2 (round-1 structure + K-split x2): z = e + 8*h, h-th K-half -> yall_h
// ==================================================================================
__global__ __launch_bounds__(256) void gemm2_kernel(
    const unsigned short* __restrict__ act, const unsigned short* __restrict__ W2T,
    const float* __restrict__ b2fp, const int* __restrict__ offs,
    const int* __restrict__ cnt, float* __restrict__ yall0, float* __restrict__ yall1) {
    const int e = blockIdx.z & 7, h = blockIdx.z >> 3;
    const int by = blockIdx.y, bx = blockIdx.x;
    const int ne = cnt[e];
    if (by * 128 >= ne) return;
    const int off_e = offs[e];
    __shared__ unsigned short Asm[2][128 * 32];
    __shared__ unsigned short Bsm[2][128 * 32];
    const int tid = threadIdx.x, w = tid >> 6, lane = tid & 63;
    const int arow0 = w * 16 + (lane >> 2);
    const int s_sw = (lane >> 3) & 3;
    const int acol = (((lane & 3) ^ s_sw) * 8);
    const int kbase = h * (DF / 2);
    int r0 = by * 128 + arow0;       if (r0 > ne - 1) r0 = ne - 1;
    int r1 = by * 128 + arow0 + 64;  if (r1 > ne - 1) r1 = ne - 1;
    const unsigned short* gA0 = act + (size_t)(off_e + r0) * DF + kbase + acol;
    const unsigned short* gA1 = act + (size_t)(off_e + r1) * DF + kbase + acol;
    const unsigned short* Wte = W2T + (size_t)e * DM * DF;
    const unsigned short* gB0 = Wte + (size_t)(bx * 128 + arow0) * DF + kbase + acol;
    const unsigned short* gB1 = gB0 + (size_t)64 * DF;
    f32x4 acc[4][4] = {};
    const int mb = (w >> 1) * 64, nb = (w & 1) * 64;
    const int rdoff = (((lane >> 4) ^ ((lane >> 1) & 3)) * 8);

#define STAGE2(buf, kk) do { \
        load_lds16(gA0 + (kk), &Asm[buf][(w) * 16 * 32]); \
        load_lds16(gA1 + (kk), &Asm[buf][(w + 4) * 16 * 32]); \
        load_lds16(gB0 + (kk), &Bsm[buf][(w) * 16 * 32]); \
        load_lds16(gB1 + (kk), &Bsm[buf][(w + 4) * 16 * 32]); \
    } while (0)

    STAGE2(0, 0);
    __syncthreads();
    int cur = 0;
    for (int kk = 0; kk < DF / 2; kk += 32) {
        if (kk + 32 < DF / 2) STAGE2(cur ^ 1, kk + 32);
        bf16x8 af[4], bfv[4];
#pragma unroll
        for (int i = 0; i < 4; i++)
            af[i] = *(const bf16x8*)&Asm[cur][(mb + i * 16 + (lane & 15)) * 32 + rdoff];
#pragma unroll
        for (int j = 0; j < 4; j++)
            bfv[j] = *(const bf16x8*)&Bsm[cur][(nb + j * 16 + (lane & 15)) * 32 + rdoff];
        __builtin_amdgcn_s_setprio(1);
#pragma unroll
        for (int i = 0; i < 4; i++)
#pragma unroll
            for (int j = 0; j < 4; j++)
                acc[i][j] = __builtin_amdgcn_mfma_f32_16x16x32_bf16(af[i], bfv[j], acc[i][j], 0, 0, 0);
        __builtin_amdgcn_s_setprio(0);
        __syncthreads();
        cur ^= 1;
    }
#undef STAGE2

    float* yall = h ? yall1 : yall0;
    const float* b2e = b2fp + (size_t)e * DM + bx * 128;
#pragma unroll
    for (int i = 0; i < 4; i++) {
#pragma unroll
        for (int r = 0; r < 4; r++) {
            int m = mb + i * 16 + ((lane >> 4) * 4) + r;
            int grow = by * 128 + m;
            if (grow < ne) {
                float* dst = yall + (size_t)(off_e + grow) * DM + bx * 128;
#pragma unroll
                for (int j = 0; j < 4; j++) {
                    int n = nb + j * 16 + (lane & 15);
                    dst[n] = acc[i][j][r] + (h ? 0.0f : b2e[n]);
                }
            }
        }
    }
}

// ---------------- combine: out[t] = s0*(y0[s0]+y1[s0]) + s1*(y0[s1]+y1[s1]) ----------------
__global__ __launch_bounds__(256) void combine_kernel(
    const float* __restrict__ yall0, const float* __restrict__ yall1,
    const int* __restrict__ slot_of, const float* __restrict__ tok_s,
    void* __restrict__ out, const int* __restrict__ flag) {
    const int t = blockIdx.x;
    const int c = threadIdx.x * 4;
    const int s0i = slot_of[2 * t], s1i = slot_of[2 * t + 1];
    const float w0 = tok_s[2 * t], w1 = tok_s[2 * t + 1];
    float4 a0 = *(const float4*)&yall0[(size_t)s0i * DM + c];
    float4 a1 = *(const float4*)&yall1[(size_t)s0i * DM + c];
    float4 b0 = *(const float4*)&yall0[(size_t)s1i * DM + c];
    float4 b1 = *(const float4*)&yall1[(size_t)s1i * DM + c];
    float4 r;
    r.x = w0 * (a0.x + a1.x) + w1 * (b0.x + b1.x);
    r.y = w0 * (a0.y + a1.y) + w1 * (b0.y + b1.y);
    r.z = w0 * (a0.z + a1.z) + w1 * (b0.z + b1.z);
    r.w = w0 * (a0.w + a1.w) + w1 * (b0.w + b1.w);
    if (*flag) {
        *(float4*)((float*)out + (size_t)t * DM + c) = r;
    } else {
        ushort4 o;
        o.x = f2b(r.x); o.y = f2b(r.y); o.z = f2b(r.z); o.w = f2b(r.w);
        *(ushort4*)((unsigned short*)out + (size_t)t * DM + c) = o;
    }
}

extern "C" void kernel_launch(void* const* d_in, const int* in_sizes, int n_in,
                              void* d_out, int out_size, void* d_ws, size_t ws_size,
                              hipStream_t stream) {
    (void)in_sizes; (void)n_in; (void)out_size; (void)ws_size;
    const void* x  = d_in[0];
    const void* W1 = d_in[1];
    const void* b1 = d_in[2];
    const void* W2 = d_in[3];
    const void* b2 = d_in[4];
    const void* Wg = d_in[5];
    const void* bg = d_in[6];

    uint8_t* wsb = (uint8_t*)d_ws;
    int* ip = (int*)wsb;
    int* flag  = ip;          // [0]
    int* cnt   = ip + 8;      // [8]
    int* cnt2  = ip + 16;     // [8] (unused, layout stability)
    int* offs  = ip + 24;     // [8]
    int* tok_e = ip + 32;     // [2T]
    float* tok_s  = (float*)(tok_e + 2 * T_TOK);
    int* tok_list = (int*)(tok_s + 2 * T_TOK);
    int* slot_of  = tok_list + 2 * T_TOK;
    size_t head = (size_t)((uint8_t*)(slot_of + 2 * T_TOK) - wsb);
    head = (head + 255) & ~(size_t)255;
    float* b1f = (float*)(wsb + head);
    float* b2f = b1f + (size_t)NE * DF;
    unsigned short* xb  = (unsigned short*)(b2f + (size_t)NE * DM);
    unsigned short* W1T = xb + (size_t)T_TOK * DM;
    unsigned short* W2T = W1T + (size_t)NE * DM * DF;
    unsigned short* actb = W2T + (size_t)NE * DM * DF;
    // overlay: W1T region (64 MB) is dead after gemm1 -> holds both K-split halves
    float* yall0 = (float*)W1T;                       // 32 MB
    float* yall1 = yall0 + (size_t)2 * T_TOK * DM;    // 32 MB
    (void)cnt2;

    hipMemsetAsync(ip, 0, 128, stream);   // zero flag (+ scratch ints)
    detect_kernel<<<256, 256, 0, stream>>>((const unsigned short*)x, flag);
    convx_kernel<<<(T_TOK * DM) / 2048, 256, 0, stream>>>(x, flag, xb);
    convf_kernel<<<(NE * (DF + DM)) / 256, 256, 0, stream>>>(b1, b2, flag, b1f, b2f);
    transpose_kernel<<<dim3(64, 16, 16), 256, 0, stream>>>(W1, W2, W1T, W2T, flag);
    gate_kernel<<<T_TOK / 4, 256, 0, stream>>>(x, Wg, bg, flag, tok_e, tok_s);
    compact_kernel<<<NE, 256, 0, stream>>>(tok_e, cnt, offs, tok_list, slot_of);
    gemm1_kernel<<<dim3(DF / 128, T_TOK / 128, NE), 256, 0, stream>>>(xb, W1T, b1f, tok_list, offs, cnt, actb);
    gemm2_kernel<<<dim3(DM / 128, T_TOK / 128, NE * 2), 256, 0, stream>>>(actb, W2T, b2f, offs, cnt, yall0, yall1);
    combine_kernel<<<T_TOK, 256, 0, stream>>>(yall0, yall1, slot_of, tok_s, d_out, flag);
}